// Round 3
// baseline (773.783 us; speedup 1.0000x reference)
//
#include <hip/hip_runtime.h>
#include <math.h>

// f32-rounded pi / 2pi (JAX weak-type f64->f32 folding): 0x40490FDB / 0x40C90FDB
#define PI_F        3.14159274101257324e0f
#define TWOPI_F     6.28318548202514648e0f
#define INV_TWOPI_F (1.0f / TWOPI_F)          // compile-time correctly-rounded f32

// dr2 < DR2_LT  <=>  __fsqrt_rn(dr2) < 0.05f, bit-exactly (proof in R1 notes):
//   boundary m = 0.05f - 2^-29; m^2 lies strictly between pred(0.0025f) and
//   0.0025f, so for f32 x:  x <= m^2  <=>  x < 0.0025f.
#define DR2_LT      0.0025f

typedef float v4f __attribute__((ext_vector_type(4)));

// Exact replication of the jnp.mod-based dphi decision in PURE f32 (R1 proof):
//  - q = truncf(dd * fl(1/2pi)); when q is the true trunc, the fma single-
//    rounds the exact remainder (f32-representable) -> bit-exact vs lax.rem;
//    the m<0 += 2pi rounded add matches jnp.mod's adjust exactly.
//  - q misrounds only when dd/2pi is ~2^-21 from an integer; there dphi ~ +/-pi
//    on BOTH paths -> dr2 ~ 9.87 >> 0.0025, decision identical.
__device__ __forceinline__ int pair_close(float ei, float ej, float pi_, float pj) {
    float deta = __fsub_rn(ei, ej);
    float dd   = __fadd_rn(__fsub_rn(pi_, pj), PI_F);
    float q    = truncf(__fmul_rn(dd, INV_TWOPI_F));
    float m    = __fmaf_rn(q, -TWOPI_F, dd);
    if (m < 0.0f) m = __fadd_rn(m, TWOPI_F);
    float dphi = __fsub_rn(m, PI_F);
    float dr2  = __fadd_rn(__fmul_rn(deta, deta), __fmul_rn(dphi, dphi));
    return dr2 < DR2_LT;
}

// Dup mask for group of N objects at offset OFF, reading from the 48-float
// register row s[] (all indices compile-time under full unroll -> stays in
// VGPRs). Pair semantics (matches the reference's sentinel construction):
//   both inactive -> dr = 0      -> dup
//   one inactive  -> dr ~ 1e6    -> not dup
//   both active   -> exact f32 dR test on raw eta/phi
template <int OFF, int N>
__device__ __forceinline__ unsigned group_dup(const float* s) {
    unsigned dup = 0;
#pragma unroll
    for (int j = 0; j < N - 1; ++j) {
        int aj = s[3 * (OFF + j)] > 0.0f;
        int d = 0;
#pragma unroll
        for (int i = j + 1; i < N; ++i) {
            int ai = s[3 * (OFF + i)] > 0.0f;
            int close = pair_close(s[3 * (OFF + i) + 1], s[3 * (OFF + j) + 1],
                                   s[3 * (OFF + i) + 2], s[3 * (OFF + j) + 2]);
            d |= (ai & aj & close) | ((ai | aj) ^ 1);
        }
        if (d) dup |= (1u << (OFF + j));
    }
    return dup;
}

// One thread per row. No LDS, no barriers, no phases:
//   - 12 independent float4 loads (192 contiguous B/lane; each 64B line is
//     touched 4x by the same lane in adjacent instructions -> MSHR-merged,
//     HBM traffic exact). Deep per-thread MLP, ~16 waves/CU resident.
//   - 24-pair mask computed entirely in registers.
//   - 12 nontemporal float4 stores (write-once stream -> no L2/L3 allocate).
__global__ __launch_bounds__(256, 4) void dup_removal_kernel(
    const v4f* __restrict__ in, v4f* __restrict__ out, int B) {
    int row = blockIdx.x * 256 + threadIdx.x;
    if (row >= B) return;

    const v4f* p = in + (size_t)row * 12;
    float s[48];
#pragma unroll
    for (int i = 0; i < 12; ++i) {
        v4f v = p[i];
        s[4 * i + 0] = v.x; s[4 * i + 1] = v.y;
        s[4 * i + 2] = v.z; s[4 * i + 3] = v.w;
    }

    unsigned dup = group_dup<0, 6>(s)     // jets      (objects 0..5)
                 | group_dup<6, 3>(s)     // electrons (objects 6..8)
                 | group_dup<9, 3>(s)     // muons     (objects 9..11)
                 | group_dup<12, 3>(s);   // photons   (objects 12..14)

    v4f* q = out + (size_t)row * 12;
#pragma unroll
    for (int i = 0; i < 12; ++i) {
        v4f w;
#pragma unroll
        for (int c = 0; c < 4; ++c) {
            int k = 4 * i + c;                       // float index 0..47
            float val = s[k];
            if (k < 45)                              // floats 45..47 = met, pass through
                val = ((dup >> (k / 3)) & 1u) ? 0.0f : val;
            w[c] = val;
        }
        __builtin_nontemporal_store(w, q + i);
    }
}

extern "C" void kernel_launch(void* const* d_in, const int* in_sizes, int n_in,
                              void* d_out, int out_size, void* d_ws, size_t ws_size,
                              hipStream_t stream) {
    const v4f* x = (const v4f*)d_in[0];
    v4f* out = (v4f*)d_out;
    int B = in_sizes[0] / 48;                            // rows of (16,3)
    int grid = (B + 255) / 256;
    dup_removal_kernel<<<grid, 256, 0, stream>>>(x, out, B);
}

// Round 4
// 303.333 us; speedup vs baseline: 2.5509x; 2.5509x over previous
//
#include <hip/hip_runtime.h>
#include <math.h>

// f32-rounded pi / 2pi (JAX weak-type f64->f32 folding): 0x40490FDB / 0x40C90FDB
#define PI_F        3.14159274101257324e0f
#define TWOPI_F     6.28318548202514648e0f
#define INV_TWOPI_F (1.0f / TWOPI_F)          // compile-time correctly-rounded f32

// dr2 < DR2_LT  <=>  __fsqrt_rn(dr2) < 0.05f, bit-exactly (proof in R1 notes):
//   boundary m = 0.05f - 2^-29; m^2 lies strictly between pred(0.0025f) and
//   0.0025f, so for f32 x:  x <= m^2  <=>  x < 0.0025f.
#define DR2_LT      0.0025f

#define ROWS_PER_BLOCK 64
#define THREADS        256
#define ROW_STRIDE     49     // 48 floats + 1 pad (odd -> conflict-free reads)

typedef float v4f __attribute__((ext_vector_type(4)));

// Exact replication of the jnp.mod-based dphi decision in PURE f32 (R1 proof):
//  - q = truncf(dd * fl(1/2pi)); when q is the true trunc, the fma single-
//    rounds the exact remainder (f32-representable) -> bit-exact vs lax.rem;
//    the m<0 += 2pi rounded add matches jnp.mod's adjust exactly.
//  - q misrounds only when dd/2pi is ~2^-21 from an integer; there dphi ~ +/-pi
//    on BOTH paths -> dr2 ~ 9.87 >> 0.0025, decision identical.
__device__ __forceinline__ int pair_close(float ei, float ej, float pi_, float pj) {
    float deta = __fsub_rn(ei, ej);
    float dd   = __fadd_rn(__fsub_rn(pi_, pj), PI_F);
    float q    = truncf(__fmul_rn(dd, INV_TWOPI_F));
    float m    = __fmaf_rn(q, -TWOPI_F, dd);
    if (m < 0.0f) m = __fadd_rn(m, TWOPI_F);
    float dphi = __fsub_rn(m, PI_F);
    float dr2  = __fadd_rn(__fmul_rn(deta, deta), __fmul_rn(dphi, dphi));
    return dr2 < DR2_LT;
}

// Component-major row layout: float u (=4f+c) of a row lives at
//   rowbuf[rl*ROW_STRIDE + 12*(u&3) + (u>>2)].
// Writers store x/y/z/w of float4 f at base+f+{0,12,24,36} (compile-time
// ds offsets, consecutive lanes stride-1 dwords -> conflict-free).
__device__ __forceinline__ float lds_at(const float* r, int u) {
    return r[12 * (u & 3) + (u >> 2)];
}

template <int OFF, int N>
__device__ __forceinline__ unsigned group_dup(const float* r) {
    float e[N], p[N];
    int   a[N];
#pragma unroll
    for (int k = 0; k < N; ++k) {
        int u = 3 * (OFF + k);
        a[k] = lds_at(r, u + 0) > 0.0f;
        e[k] = lds_at(r, u + 1);
        p[k] = lds_at(r, u + 2);
    }
    unsigned dup = 0;
#pragma unroll
    for (int j = 0; j < N - 1; ++j) {
        int d = 0;
#pragma unroll
        for (int i = j + 1; i < N; ++i) {
            int close = pair_close(e[i], e[j], p[i], p[j]);
            d |= (a[i] & a[j] & close) | ((a[i] | a[j]) ^ 1);
        }
        if (d) dup |= (1u << (OFF + j));
    }
    return dup;
}

// Block = 256 threads handling 64 rows (3 float4 per thread) -- the R2
// structure (best measured), plus NONTEMPORAL load/store hints:
// both streams are touch-once (input never re-read, output never read), so
// skipping L2/L3 allocation avoids churning 384 MB through the 256 MB L3
// between the harness's 768 MB fills. Stores remain wave-contiguous 4 KB
// segments -> full 64B lines, no R3-style write amplification.
template <bool FULL>
__device__ __forceinline__ void block_body(
    const v4f* __restrict__ in, v4f* __restrict__ out, int B,
    float* rowbuf, unsigned long long* maskbuf) {
    const int t = threadIdx.x;
    const int base4  = blockIdx.x * (ROWS_PER_BLOCK * 12);   // < 12M, fits int
    const int total4 = B * 12;

#pragma unroll
    for (int i = 0; i < 3; ++i) {
        int g = base4 + t + THREADS * i;
        if (FULL || g < total4) {
            v4f v = __builtin_nontemporal_load(in + g);
            int local = t + THREADS * i;
            int rl = local / 12;
            int f  = local - rl * 12;
            float* dstp = &rowbuf[rl * ROW_STRIDE + f];
            dstp[0] = v.x; dstp[12] = v.y; dstp[24] = v.z; dstp[36] = v.w;
        }
    }
    __syncthreads();

    if (t < ROWS_PER_BLOCK) {
        int row = blockIdx.x * ROWS_PER_BLOCK + t;
        unsigned dup = 0;
        if (FULL || row < B) {
            const float* r = rowbuf + t * ROW_STRIDE;
            dup  = group_dup<0, 6>(r);    // jets      (objects 0..5)
            dup |= group_dup<6, 3>(r);    // electrons (objects 6..8)
            dup |= group_dup<9, 3>(r);    // muons     (objects 9..11)
            dup |= group_dup<12, 3>(r);   // photons   (objects 12..14)
        }
        // expand object mask -> per-float mask (bit k = zero float k, k=0..44)
        unsigned long long fm = 0ull;
#pragma unroll
        for (int o = 0; o < 15; ++o)
            fm |= (unsigned long long)((dup >> o) & 1u) * (7ull << (3 * o));
        maskbuf[t] = fm;
    }
    __syncthreads();

#pragma unroll
    for (int i = 0; i < 3; ++i) {
        int g = base4 + t + THREADS * i;
        if (FULL || g < total4) {
            int local = t + THREADS * i;
            int rl = local / 12;
            int f  = local - rl * 12;
            unsigned nib = (unsigned)(maskbuf[rl] >> (4 * f)) & 0xFu;
            const float* srcp = &rowbuf[rl * ROW_STRIDE + f];
            v4f w;
            w.x = (nib & 1u) ? 0.0f : srcp[0];
            w.y = (nib & 2u) ? 0.0f : srcp[12];
            w.z = (nib & 4u) ? 0.0f : srcp[24];
            w.w = (nib & 8u) ? 0.0f : srcp[36];
            __builtin_nontemporal_store(w, out + g);
        }
    }
}

__global__ __launch_bounds__(THREADS, 8) void dup_removal_kernel(
    const v4f* __restrict__ in, v4f* __restrict__ out, int B) {
    __shared__ float rowbuf[ROWS_PER_BLOCK * ROW_STRIDE];   // 12.25 KB
    __shared__ unsigned long long maskbuf[ROWS_PER_BLOCK];  // 0.5 KB

    const int base4  = blockIdx.x * (ROWS_PER_BLOCK * 12);
    const int total4 = B * 12;
    if (base4 + ROWS_PER_BLOCK * 12 <= total4)
        block_body<true>(in, out, B, rowbuf, maskbuf);
    else
        block_body<false>(in, out, B, rowbuf, maskbuf);
}

extern "C" void kernel_launch(void* const* d_in, const int* in_sizes, int n_in,
                              void* d_out, int out_size, void* d_ws, size_t ws_size,
                              hipStream_t stream) {
    const v4f* x = (const v4f*)d_in[0];
    v4f* out = (v4f*)d_out;
    int B = in_sizes[0] / 48;                            // rows of (16,3)
    int grid = (B + ROWS_PER_BLOCK - 1) / ROWS_PER_BLOCK;
    dup_removal_kernel<<<grid, THREADS, 0, stream>>>(x, out, B);
}